// Round 4
// baseline (496.777 us; speedup 1.0000x reference)
//
#include <hip/hip_runtime.h>

#define IN_F 128
#define HID 64
#define NCLS 4
#define BN_EPS 1e-5f

#define MAXB 512        // max buckets (n <= 131072)
#define BSH 8           // bucket = dst >> 8  (256 nodes per bucket)
#define CHUNK 4096      // edges per block in chunked passes

// ---------------- CSR build ----------------

__global__ void k_init(int* __restrict__ degi, float* __restrict__ stats,
                       int* __restrict__ bhist, int n) {
    int i = blockIdx.x * blockDim.x + threadIdx.x;
    if (i < n) degi[i] = 0;
    if (i < 256) stats[i] = 0.f;
    if (i < MAXB) bhist[i] = 0;
}

// per-node degree + per-bucket histogram (chunked, LDS-staged flush)
__global__ __launch_bounds__(256) void k_count(const int* __restrict__ dst,
                                               int* __restrict__ degi,
                                               int* __restrict__ bhist, int e) {
    __shared__ int lh[MAXB];
    int t = threadIdx.x;
    for (int i = t; i < MAXB; i += 256) lh[i] = 0;
    __syncthreads();
    int base = blockIdx.x * CHUNK;
    int m = min(CHUNK, e - base);
    for (int i = t; i < m; i += 256) {
        int d = dst[base + i];
        atomicAdd(&degi[d], 1);
        atomicAdd(&lh[d >> BSH], 1);
    }
    __syncthreads();
    for (int b = t; b < MAXB; b += 256) { int c = lh[b]; if (c) atomicAdd(&bhist[b], c); }
}

// ---- parallel exclusive scan of degi -> rowptr/cursor, plus dinv ----
__global__ __launch_bounds__(256) void k_scan1(const int* __restrict__ degi,
                                               int* __restrict__ part, int n) {
    int t = threadIdx.x;
    int base = blockIdx.x * 1024 + t * 4;
    int s = 0;
#pragma unroll
    for (int j = 0; j < 4; ++j) { int i = base + j; if (i < n) s += degi[i]; }
    __shared__ int red[256];
    red[t] = s; __syncthreads();
    for (int off = 128; off > 0; off >>= 1) {
        if (t < off) red[t] += red[t + off];
        __syncthreads();
    }
    if (t == 0) part[blockIdx.x] = red[0];
}

__global__ __launch_bounds__(1024) void k_scan2(int* __restrict__ part, int nb) {
    __shared__ int sh[1024];
    int t = threadIdx.x;
    int v = (t < nb) ? part[t] : 0;
    sh[t] = v; __syncthreads();
    for (int off = 1; off < 1024; off <<= 1) {
        int add = (t >= off) ? sh[t - off] : 0;
        __syncthreads();
        sh[t] += add;
        __syncthreads();
    }
    if (t < nb) part[t] = sh[t] - v;   // exclusive
}

__global__ __launch_bounds__(256) void k_scan3(const int* __restrict__ degi,
                                               const int* __restrict__ part,
                                               int* __restrict__ rowptr,
                                               int* __restrict__ cursor,
                                               float* __restrict__ dinv,
                                               int n, int e) {
    int t = threadIdx.x;
    int base = blockIdx.x * 1024 + t * 4;
    int d[4]; int s = 0;
#pragma unroll
    for (int j = 0; j < 4; ++j) { int i = base + j; d[j] = (i < n) ? degi[i] : 0; s += d[j]; }
    __shared__ int sh[256];
    sh[t] = s; __syncthreads();
    for (int off = 1; off < 256; off <<= 1) {
        int add = (t >= off) ? sh[t - off] : 0;
        __syncthreads();
        sh[t] += add;
        __syncthreads();
    }
    int run = part[blockIdx.x] + sh[t] - s;
#pragma unroll
    for (int j = 0; j < 4; ++j) {
        int i = base + j;
        if (i < n) {
            rowptr[i] = run;
            cursor[i] = run;
            dinv[i] = 1.0f / sqrtf((float)(d[j] + 1));   // deg includes self-loop
            run += d[j];
        }
    }
    if (blockIdx.x == 0 && t == 0) rowptr[n] = e;
}

// exclusive scan of bucket histogram -> boff, bcur
__global__ __launch_bounds__(512) void k_bscan(const int* __restrict__ bhist,
                                               int* __restrict__ boff,
                                               int* __restrict__ bcur,
                                               int nbkt, int e) {
    __shared__ int sh[512];
    int t = threadIdx.x;
    int v = (t < nbkt) ? bhist[t] : 0;
    sh[t] = v; __syncthreads();
    for (int off = 1; off < 512; off <<= 1) {
        int add = (t >= off) ? sh[t - off] : 0;
        __syncthreads();
        sh[t] += add;
        __syncthreads();
    }
    if (t < nbkt) { int ex = sh[t] - v; boff[t] = ex; bcur[t] = ex; }
    if (t == 0) boff[nbkt] = e;
}

// phase A: bin (src,dst) pairs by dst-bucket with LDS multisplit, coalesced writes
__global__ __launch_bounds__(256) void k_bin(const int* __restrict__ src,
                                             const int* __restrict__ dst,
                                             int* __restrict__ bcur,
                                             uint2* __restrict__ pairs, int e) {
    __shared__ uint2 stage[CHUNK];
    __shared__ int cnt[MAXB], off[MAXB], gbase[MAXB];
    int t = threadIdx.x;
    for (int i = t; i < MAXB; i += 256) cnt[i] = 0;
    __syncthreads();
    int base = blockIdx.x * CHUNK;
    int m = min(CHUNK, e - base);
    int lr[CHUNK / 256];
#pragma unroll
    for (int j = 0; j < CHUNK / 256; ++j) {
        int i = t + j * 256;
        if (i < m) lr[j] = atomicAdd(&cnt[dst[base + i] >> BSH], 1);
    }
    __syncthreads();
    // inclusive scan of cnt (512 entries, 256 threads, Hillis-Steele, 2/thread)
    off[t] = cnt[t]; off[t + 256] = cnt[t + 256];
    __syncthreads();
    for (int o = 1; o < 512; o <<= 1) {
        int v0 = (t >= o) ? off[t - o] : 0;
        int v1 = (t + 256 >= o) ? off[t + 256 - o] : 0;
        __syncthreads();
        off[t] += v0; off[t + 256] += v1;
        __syncthreads();
    }
    // reserve global range; bias so global addr = gbase[b] + stage_index
    for (int b = t; b < MAXB; b += 256) {
        int c = cnt[b];
        int ex = off[b] - c;                       // exclusive local offset
        gbase[b] = c ? (atomicAdd(&bcur[b], c) - ex) : 0;
    }
    __syncthreads();
#pragma unroll
    for (int j = 0; j < CHUNK / 256; ++j) {
        int i = t + j * 256;
        if (i < m) {
            int s = src[base + i], d = dst[base + i];
            int b = d >> BSH;
            stage[(off[b] - cnt[b]) + lr[j]] = make_uint2((unsigned)s, (unsigned)d);
        }
    }
    __syncthreads();
    for (int i = t; i < m; i += 256) {
        uint2 p = stage[i];
        int b = (int)(p.y >> BSH);
        pairs[gbase[b] + i] = p;
    }
}

// phase B: per-bucket scatter into csr (scatter span ~16KB -> stays in L2)
__global__ __launch_bounds__(256) void k_fill2(const uint2* __restrict__ pairs,
                                               const int* __restrict__ boff,
                                               int* __restrict__ cursor,
                                               int* __restrict__ csr) {
    int b = blockIdx.x;
    int beg = boff[b], end = boff[b + 1];
    for (int i = beg + threadIdx.x; i < end; i += 256) {
        uint2 p = pairs[i];
        int pos = atomicAdd(&cursor[p.y], 1);
        csr[pos] = (int)p.x;
    }
}

// ---------------- GEMMs (thread-per-row, W in LDS) ----------------

__global__ __launch_bounds__(256) void k_gemm1(const float* __restrict__ x,
                                               const float* __restrict__ W,
                                               const float* __restrict__ dinv,
                                               float* __restrict__ hs, int n) {
    __shared__ float4 Ws[IN_F * HID / 4];   // 32 KB
    int t = threadIdx.x;
    const float4* W4 = (const float4*)W;
#pragma unroll
    for (int i = 0; i < 8; ++i) Ws[t + i * 256] = W4[t + i * 256];
    __syncthreads();
    int r = blockIdx.x * 256 + t;
    if (r >= n) return;
    float4 acc[16];
#pragma unroll
    for (int j = 0; j < 16; ++j) acc[j] = make_float4(0.f, 0.f, 0.f, 0.f);
    const float4* xr = (const float4*)(x + (size_t)r * IN_F);
    for (int kk = 0; kk < 32; ++kk) {
        float4 xv = xr[kk];
#pragma unroll
        for (int l = 0; l < 4; ++l) {
            float xs = (l == 0) ? xv.x : (l == 1) ? xv.y : (l == 2) ? xv.z : xv.w;
            const float4* wr = &Ws[(kk * 4 + l) * 16];
#pragma unroll
            for (int j = 0; j < 16; ++j) {
                float4 w = wr[j];
                acc[j].x += xs * w.x; acc[j].y += xs * w.y;
                acc[j].z += xs * w.z; acc[j].w += xs * w.w;
            }
        }
    }
    float dv = dinv[r];
    float4* out = (float4*)(hs + (size_t)r * HID);
#pragma unroll
    for (int j = 0; j < 16; ++j)
        out[j] = make_float4(acc[j].x * dv, acc[j].y * dv, acc[j].z * dv, acc[j].w * dv);
}

__global__ __launch_bounds__(256) void k_gemm2(const float* __restrict__ z,
                                               const float* __restrict__ W,
                                               const float* __restrict__ scsh,
                                               const float* __restrict__ dinv,
                                               float* __restrict__ hs, int n) {
    __shared__ float4 Ws[HID * HID / 4];    // 16 KB
    __shared__ float sc[64], sh[64];
    int t = threadIdx.x;
    const float4* W4 = (const float4*)W;
#pragma unroll
    for (int i = 0; i < 4; ++i) Ws[t + i * 256] = W4[t + i * 256];
    if (t < 64) { sc[t] = scsh[t]; sh[t] = scsh[64 + t]; }
    __syncthreads();
    int r = blockIdx.x * 256 + t;
    if (r >= n) return;
    float4 acc[16];
#pragma unroll
    for (int j = 0; j < 16; ++j) acc[j] = make_float4(0.f, 0.f, 0.f, 0.f);
    const float4* zr = (const float4*)(z + (size_t)r * HID);
    for (int kk = 0; kk < 16; ++kk) {
        float4 zv = zr[kk];
#pragma unroll
        for (int l = 0; l < 4; ++l) {
            int k = kk * 4 + l;
            float zs = (l == 0) ? zv.x : (l == 1) ? zv.y : (l == 2) ? zv.z : zv.w;
            float a = fmaxf(0.f, zs * sc[k] + sh[k]);
            const float4* wr = &Ws[k * 16];
#pragma unroll
            for (int j = 0; j < 16; ++j) {
                float4 w = wr[j];
                acc[j].x += a * w.x; acc[j].y += a * w.y;
                acc[j].z += a * w.z; acc[j].w += a * w.w;
            }
        }
    }
    float dv = dinv[r];
    float4* out = (float4*)(hs + (size_t)r * HID);
#pragma unroll
    for (int j = 0; j < 16; ++j)
        out[j] = make_float4(acc[j].x * dv, acc[j].y * dv, acc[j].z * dv, acc[j].w * dv);
}

__global__ __launch_bounds__(256) void k_gemm3(const float* __restrict__ z,
                                               const float* __restrict__ W,
                                               const float* __restrict__ scsh,
                                               const float* __restrict__ dinv,
                                               float* __restrict__ hs3, int n) {
    __shared__ float4 Ws[64];
    __shared__ float sc[64], sh[64];
    int t = threadIdx.x;
    if (t < 64) { Ws[t] = ((const float4*)W)[t]; sc[t] = scsh[t]; sh[t] = scsh[64 + t]; }
    __syncthreads();
    int r = blockIdx.x * 256 + t;
    if (r >= n) return;
    float4 acc = make_float4(0.f, 0.f, 0.f, 0.f);
    const float4* zr = (const float4*)(z + (size_t)r * HID);
    for (int kk = 0; kk < 16; ++kk) {
        float4 zv = zr[kk];
#pragma unroll
        for (int l = 0; l < 4; ++l) {
            int k = kk * 4 + l;
            float zs = (l == 0) ? zv.x : (l == 1) ? zv.y : (l == 2) ? zv.z : zv.w;
            float a = fmaxf(0.f, zs * sc[k] + sh[k]);
            float4 w = Ws[k];
            acc.x += a * w.x; acc.y += a * w.y; acc.z += a * w.z; acc.w += a * w.w;
        }
    }
    float dv = dinv[r];
    ((float4*)hs3)[r] = make_float4(acc.x * dv, acc.y * dv, acc.z * dv, acc.w * dv);
}

// ---------------- Aggregation (CSR gather) ----------------

// z[i,:] = dinv[i] * (hs[i,:] + sum_{s in nbr(i)} hs[s,:]) + bias
// 16 lanes per node (c4 = channel quad); edge loop unrolled x4 with 4
// independent accumulators for memory-level parallelism.
__global__ __launch_bounds__(256) void k_agg64(const float* __restrict__ hs,
                                               const int* __restrict__ rowptr,
                                               const int* __restrict__ csr,
                                               const float* __restrict__ dinv,
                                               const float* __restrict__ bias,
                                               float* __restrict__ z,
                                               float* __restrict__ sums,
                                               float* __restrict__ sumsq, int n) {
    __shared__ float lsum[64], lsq[64];
    int t = threadIdx.x;
    if (t < 64) { lsum[t] = 0.f; lsq[t] = 0.f; }
    __syncthreads();
    const float4* h4 = (const float4*)hs;
    long long total = (long long)n * 16;
    int stride = gridDim.x * blockDim.x;      // multiple of 16 -> c4 invariant
    int gid = blockIdx.x * blockDim.x + t;
    int c4 = gid & 15;
    float4 bv = ((const float4*)bias)[c4];
    float ps0 = 0.f, ps1 = 0.f, ps2 = 0.f, ps3 = 0.f;
    float pq0 = 0.f, pq1 = 0.f, pq2 = 0.f, pq3 = 0.f;
    for (long long w = gid; w < total; w += stride) {
        int i = (int)(w >> 4);
        float4 a0 = h4[(size_t)i * 16 + c4];          // self-loop term
        float4 a1 = make_float4(0.f, 0.f, 0.f, 0.f);
        float4 a2 = make_float4(0.f, 0.f, 0.f, 0.f);
        float4 a3 = make_float4(0.f, 0.f, 0.f, 0.f);
        int beg = rowptr[i], end = rowptr[i + 1];
        int j = beg;
        for (; j + 4 <= end; j += 4) {
            int s0 = csr[j], s1 = csr[j + 1], s2 = csr[j + 2], s3 = csr[j + 3];
            float4 v0 = h4[(size_t)s0 * 16 + c4];
            float4 v1 = h4[(size_t)s1 * 16 + c4];
            float4 v2 = h4[(size_t)s2 * 16 + c4];
            float4 v3 = h4[(size_t)s3 * 16 + c4];
            a0.x += v0.x; a0.y += v0.y; a0.z += v0.z; a0.w += v0.w;
            a1.x += v1.x; a1.y += v1.y; a1.z += v1.z; a1.w += v1.w;
            a2.x += v2.x; a2.y += v2.y; a2.z += v2.z; a2.w += v2.w;
            a3.x += v3.x; a3.y += v3.y; a3.z += v3.z; a3.w += v3.w;
        }
        for (; j < end; ++j) {
            int s = csr[j];
            float4 v = h4[(size_t)s * 16 + c4];
            a0.x += v.x; a0.y += v.y; a0.z += v.z; a0.w += v.w;
        }
        float4 acc = make_float4((a0.x + a1.x) + (a2.x + a3.x),
                                 (a0.y + a1.y) + (a2.y + a3.y),
                                 (a0.z + a1.z) + (a2.z + a3.z),
                                 (a0.w + a1.w) + (a2.w + a3.w));
        float dv = dinv[i];
        float4 zv = make_float4(acc.x * dv + bv.x, acc.y * dv + bv.y,
                                acc.z * dv + bv.z, acc.w * dv + bv.w);
        ((float4*)z)[(size_t)i * 16 + c4] = zv;
        ps0 += zv.x; ps1 += zv.y; ps2 += zv.z; ps3 += zv.w;
        pq0 += zv.x * zv.x; pq1 += zv.y * zv.y; pq2 += zv.z * zv.z; pq3 += zv.w * zv.w;
    }
    int cb = c4 * 4;
    atomicAdd(&lsum[cb + 0], ps0); atomicAdd(&lsum[cb + 1], ps1);
    atomicAdd(&lsum[cb + 2], ps2); atomicAdd(&lsum[cb + 3], ps3);
    atomicAdd(&lsq[cb + 0], pq0);  atomicAdd(&lsq[cb + 1], pq1);
    atomicAdd(&lsq[cb + 2], pq2);  atomicAdd(&lsq[cb + 3], pq3);
    __syncthreads();
    if (t < 64) { atomicAdd(&sums[t], lsum[t]); atomicAdd(&sumsq[t], lsq[t]); }
}

__global__ void k_agg4(const float* __restrict__ hs3, const int* __restrict__ rowptr,
                       const int* __restrict__ csr, const float* __restrict__ dinv,
                       const float* __restrict__ b3, float* __restrict__ out, int n) {
    int i = blockIdx.x * blockDim.x + threadIdx.x;
    if (i >= n) return;
    const float4* h4 = (const float4*)hs3;
    float4 a0 = h4[i];
    float4 a1 = make_float4(0.f, 0.f, 0.f, 0.f);
    float4 a2 = make_float4(0.f, 0.f, 0.f, 0.f);
    float4 a3 = make_float4(0.f, 0.f, 0.f, 0.f);
    int beg = rowptr[i], end = rowptr[i + 1];
    int j = beg;
    for (; j + 4 <= end; j += 4) {
        int s0 = csr[j], s1 = csr[j + 1], s2 = csr[j + 2], s3 = csr[j + 3];
        float4 v0 = h4[s0], v1 = h4[s1], v2 = h4[s2], v3 = h4[s3];
        a0.x += v0.x; a0.y += v0.y; a0.z += v0.z; a0.w += v0.w;
        a1.x += v1.x; a1.y += v1.y; a1.z += v1.z; a1.w += v1.w;
        a2.x += v2.x; a2.y += v2.y; a2.z += v2.z; a2.w += v2.w;
        a3.x += v3.x; a3.y += v3.y; a3.z += v3.z; a3.w += v3.w;
    }
    for (; j < end; ++j) {
        float4 v = h4[csr[j]];
        a0.x += v.x; a0.y += v.y; a0.z += v.z; a0.w += v.w;
    }
    float4 acc = make_float4((a0.x + a1.x) + (a2.x + a3.x),
                             (a0.y + a1.y) + (a2.y + a3.y),
                             (a0.z + a1.z) + (a2.z + a3.z),
                             (a0.w + a1.w) + (a2.w + a3.w));
    float dv = dinv[i];
    float4 bv = *(const float4*)b3;
    ((float4*)out)[i] = make_float4(acc.x * dv + bv.x, acc.y * dv + bv.y,
                                    acc.z * dv + bv.z, acc.w * dv + bv.w);
}

__global__ void k_bnstats(const float* __restrict__ sums, const float* __restrict__ sumsq,
                          const float* __restrict__ g, const float* __restrict__ be,
                          float* __restrict__ scsh, int n) {
    int t = threadIdx.x;
    if (t < 64) {
        float inv_n = 1.f / (float)n;
        float m = sums[t] * inv_n;
        float v = sumsq[t] * inv_n - m * m;
        float sc = g[t] / sqrtf(v + BN_EPS);
        scsh[t] = sc;
        scsh[64 + t] = be[t] - m * sc;
    }
}

// ---------------- launch ----------------

extern "C" void kernel_launch(void* const* d_in, const int* in_sizes, int n_in,
                              void* d_out, int out_size, void* d_ws, size_t ws_size,
                              hipStream_t stream) {
    const float* x   = (const float*)d_in[0];
    const int*   ei  = (const int*)d_in[1];
    const float* W1  = (const float*)d_in[2];
    const float* b1  = (const float*)d_in[3];
    const float* g1  = (const float*)d_in[4];
    const float* be1 = (const float*)d_in[5];
    const float* W2  = (const float*)d_in[6];
    const float* b2  = (const float*)d_in[7];
    const float* g2  = (const float*)d_in[8];
    const float* be2 = (const float*)d_in[9];
    const float* W3  = (const float*)d_in[10];
    const float* b3  = (const float*)d_in[11];

    int n = in_sizes[0] / IN_F;
    int e = in_sizes[1] / 2;
    const int* src = ei;
    const int* dst = ei + e;

    float* wsf = (float*)d_ws;
    size_t NP = ((size_t)(n + 256) + 255) & ~(size_t)255;
    size_t EP = ((size_t)e + 255) & ~(size_t)255;
    size_t NB = (((size_t)n * HID) + 255) & ~(size_t)255;

    int*   degi   = (int*)wsf;
    float* dinv   = wsf + NP;
    int*   rowptr = (int*)(wsf + 2 * NP);
    int*   cursor = (int*)(wsf + 3 * NP);
    float* stats  = wsf + 4 * NP;          // 256
    float* scsh   = stats + 256;           // 256
    int*   part   = (int*)(scsh + 256);    // 1024
    int*   bhist  = part + 1024;           // 512
    int*   boff   = bhist + 512;           // 520
    int*   bcur   = boff + 520;            // 512
    int*   csr    = bcur + 512;
    float* A      = (float*)csr + EP;      // hs buffer [n,64]
    float* B      = A + NB;                // z  buffer [n,64]
    float* hs3    = B + NB;                // [n,4]
    uint2* pairs  = (uint2*)B;             // alias: B first written after fill2 reads

    int nb = (n + 255) / 256;
    int eb = (e + CHUNK - 1) / CHUNK;      // chunked edge blocks
    int sb = (n + 1023) / 1024;
    int nbkt = (n + 255) >> BSH;           // buckets

    k_init <<<nb, 256, 0, stream>>>(degi, stats, bhist, n);
    k_count<<<eb, 256, 0, stream>>>(dst, degi, bhist, e);
    k_scan1<<<sb, 256, 0, stream>>>(degi, part, n);
    k_scan2<<<1, 1024, 0, stream>>>(part, sb);
    k_scan3<<<sb, 256, 0, stream>>>(degi, part, rowptr, cursor, dinv, n, e);
    k_bscan<<<1, 512, 0, stream>>>(bhist, boff, bcur, nbkt, e);
    k_bin  <<<eb, 256, 0, stream>>>(src, dst, bcur, pairs, e);
    k_fill2<<<nbkt, 256, 0, stream>>>(pairs, boff, cursor, csr);

    // layer 1
    k_gemm1<<<nb, 256, 0, stream>>>(x, W1, dinv, A, n);
    k_agg64<<<2048, 256, 0, stream>>>(A, rowptr, csr, dinv, b1, B, stats, stats + 64, n);
    k_bnstats<<<1, 64, 0, stream>>>(stats, stats + 64, g1, be1, scsh, n);

    // layer 2
    k_gemm2<<<nb, 256, 0, stream>>>(B, W2, scsh, dinv, A, n);
    k_agg64<<<2048, 256, 0, stream>>>(A, rowptr, csr, dinv, b2, B, stats + 128, stats + 192, n);
    k_bnstats<<<1, 64, 0, stream>>>(stats + 128, stats + 192, g2, be2, scsh + 128, n);

    // layer 3
    k_gemm3<<<nb, 256, 0, stream>>>(B, W3, scsh + 128, dinv, hs3, n);
    k_agg4 <<<nb, 256, 0, stream>>>(hs3, rowptr, csr, dinv, b3, (float*)d_out, n);
}

// Round 5
// 428.285 us; speedup vs baseline: 1.1599x; 1.1599x over previous
//
#include <hip/hip_runtime.h>
#include <hip/hip_fp16.h>

#define IN_F 128
#define HID 64
#define NCLS 4
#define BN_EPS 1e-5f

#define MAXB 512        // max buckets (n <= 131072)
#define BSH 8           // bucket = dst >> 8  (256 nodes per bucket)
#define CHUNK 4096      // edges per block in chunked passes

// ---------------- CSR build ----------------

__global__ void k_init(int* __restrict__ degi, float* __restrict__ stats,
                       int* __restrict__ bhist, int n) {
    int i = blockIdx.x * blockDim.x + threadIdx.x;
    if (i < n) degi[i] = 0;
    if (i < 256) stats[i] = 0.f;
    if (i < MAXB) bhist[i] = 0;
}

// per-node degree + per-bucket histogram (chunked, LDS-staged flush)
__global__ __launch_bounds__(256) void k_count(const int* __restrict__ dst,
                                               int* __restrict__ degi,
                                               int* __restrict__ bhist, int e) {
    __shared__ int lh[MAXB];
    int t = threadIdx.x;
    for (int i = t; i < MAXB; i += 256) lh[i] = 0;
    __syncthreads();
    int base = blockIdx.x * CHUNK;
    int m = min(CHUNK, e - base);
    for (int i = t; i < m; i += 256) {
        int d = dst[base + i];
        atomicAdd(&degi[d], 1);
        atomicAdd(&lh[d >> BSH], 1);
    }
    __syncthreads();
    for (int b = t; b < MAXB; b += 256) { int c = lh[b]; if (c) atomicAdd(&bhist[b], c); }
}

// ---- parallel exclusive scan of degi -> rowptr/cursor, plus dinv ----
__global__ __launch_bounds__(256) void k_scan1(const int* __restrict__ degi,
                                               int* __restrict__ part, int n) {
    int t = threadIdx.x;
    int base = blockIdx.x * 1024 + t * 4;
    int s = 0;
#pragma unroll
    for (int j = 0; j < 4; ++j) { int i = base + j; if (i < n) s += degi[i]; }
    __shared__ int red[256];
    red[t] = s; __syncthreads();
    for (int off = 128; off > 0; off >>= 1) {
        if (t < off) red[t] += red[t + off];
        __syncthreads();
    }
    if (t == 0) part[blockIdx.x] = red[0];
}

__global__ __launch_bounds__(1024) void k_scan2(int* __restrict__ part, int nb) {
    __shared__ int sh[1024];
    int t = threadIdx.x;
    int v = (t < nb) ? part[t] : 0;
    sh[t] = v; __syncthreads();
    for (int off = 1; off < 1024; off <<= 1) {
        int add = (t >= off) ? sh[t - off] : 0;
        __syncthreads();
        sh[t] += add;
        __syncthreads();
    }
    if (t < nb) part[t] = sh[t] - v;   // exclusive
}

__global__ __launch_bounds__(256) void k_scan3(const int* __restrict__ degi,
                                               const int* __restrict__ part,
                                               int* __restrict__ rowptr,
                                               int* __restrict__ cursor,
                                               float* __restrict__ dinv,
                                               int n, int e) {
    int t = threadIdx.x;
    int base = blockIdx.x * 1024 + t * 4;
    int d[4]; int s = 0;
#pragma unroll
    for (int j = 0; j < 4; ++j) { int i = base + j; d[j] = (i < n) ? degi[i] : 0; s += d[j]; }
    __shared__ int sh[256];
    sh[t] = s; __syncthreads();
    for (int off = 1; off < 256; off <<= 1) {
        int add = (t >= off) ? sh[t - off] : 0;
        __syncthreads();
        sh[t] += add;
        __syncthreads();
    }
    int run = part[blockIdx.x] + sh[t] - s;
#pragma unroll
    for (int j = 0; j < 4; ++j) {
        int i = base + j;
        if (i < n) {
            rowptr[i] = run;
            cursor[i] = run;
            dinv[i] = 1.0f / sqrtf((float)(d[j] + 1));   // deg includes self-loop
            run += d[j];
        }
    }
    if (blockIdx.x == 0 && t == 0) rowptr[n] = e;
}

// exclusive scan of bucket histogram -> boff, bcur
__global__ __launch_bounds__(512) void k_bscan(const int* __restrict__ bhist,
                                               int* __restrict__ boff,
                                               int* __restrict__ bcur,
                                               int nbkt, int e) {
    __shared__ int sh[512];
    int t = threadIdx.x;
    int v = (t < nbkt) ? bhist[t] : 0;
    sh[t] = v; __syncthreads();
    for (int off = 1; off < 512; off <<= 1) {
        int add = (t >= off) ? sh[t - off] : 0;
        __syncthreads();
        sh[t] += add;
        __syncthreads();
    }
    if (t < nbkt) { int ex = sh[t] - v; boff[t] = ex; bcur[t] = ex; }
    if (t == 0) boff[nbkt] = e;
}

// phase A: bin (src,dst) pairs by dst-bucket with LDS multisplit, coalesced writes
__global__ __launch_bounds__(256) void k_bin(const int* __restrict__ src,
                                             const int* __restrict__ dst,
                                             int* __restrict__ bcur,
                                             uint2* __restrict__ pairs, int e) {
    __shared__ uint2 stage[CHUNK];
    __shared__ int cnt[MAXB], off[MAXB], gbase[MAXB];
    int t = threadIdx.x;
    for (int i = t; i < MAXB; i += 256) cnt[i] = 0;
    __syncthreads();
    int base = blockIdx.x * CHUNK;
    int m = min(CHUNK, e - base);
    int lr[CHUNK / 256];
#pragma unroll
    for (int j = 0; j < CHUNK / 256; ++j) {
        int i = t + j * 256;
        if (i < m) lr[j] = atomicAdd(&cnt[dst[base + i] >> BSH], 1);
    }
    __syncthreads();
    // inclusive scan of cnt (512 entries, 256 threads, Hillis-Steele, 2/thread)
    off[t] = cnt[t]; off[t + 256] = cnt[t + 256];
    __syncthreads();
    for (int o = 1; o < 512; o <<= 1) {
        int v0 = (t >= o) ? off[t - o] : 0;
        int v1 = (t + 256 >= o) ? off[t + 256 - o] : 0;
        __syncthreads();
        off[t] += v0; off[t + 256] += v1;
        __syncthreads();
    }
    // reserve global range; bias so global addr = gbase[b] + stage_index
    for (int b = t; b < MAXB; b += 256) {
        int c = cnt[b];
        int ex = off[b] - c;                       // exclusive local offset
        gbase[b] = c ? (atomicAdd(&bcur[b], c) - ex) : 0;
    }
    __syncthreads();
#pragma unroll
    for (int j = 0; j < CHUNK / 256; ++j) {
        int i = t + j * 256;
        if (i < m) {
            int s = src[base + i], d = dst[base + i];
            int b = d >> BSH;
            stage[(off[b] - cnt[b]) + lr[j]] = make_uint2((unsigned)s, (unsigned)d);
        }
    }
    __syncthreads();
    for (int i = t; i < m; i += 256) {
        uint2 p = stage[i];
        int b = (int)(p.y >> BSH);
        pairs[gbase[b] + i] = p;
    }
}

// phase B: per-bucket scatter into csr (scatter span ~16KB -> stays in L2)
__global__ __launch_bounds__(256) void k_fill2(const uint2* __restrict__ pairs,
                                               const int* __restrict__ boff,
                                               int* __restrict__ cursor,
                                               int* __restrict__ csr) {
    int b = blockIdx.x;
    int beg = boff[b], end = boff[b + 1];
    for (int i = beg + threadIdx.x; i < end; i += 256) {
        uint2 p = pairs[i];
        int pos = atomicAdd(&cursor[p.y], 1);
        csr[pos] = (int)p.x;
    }
}

// ---------------- GEMMs (thread-per-row, W in LDS; fp16 staged output) ----------------

// hsA[r,:] = half((x[r,:] @ W1) * dinv[r])
__global__ __launch_bounds__(256) void k_gemm1(const float* __restrict__ x,
                                               const float* __restrict__ W,
                                               const float* __restrict__ dinv,
                                               __half* __restrict__ hsA, int n) {
    __shared__ float4 Ws[IN_F * HID / 4];   // 32 KB
    int t = threadIdx.x;
    const float4* W4 = (const float4*)W;
#pragma unroll
    for (int i = 0; i < 8; ++i) Ws[t + i * 256] = W4[t + i * 256];
    __syncthreads();
    int r = blockIdx.x * 256 + t;
    if (r >= n) return;
    float4 acc[16];
#pragma unroll
    for (int j = 0; j < 16; ++j) acc[j] = make_float4(0.f, 0.f, 0.f, 0.f);
    const float4* xr = (const float4*)(x + (size_t)r * IN_F);
    for (int kk = 0; kk < 32; ++kk) {
        float4 xv = xr[kk];
#pragma unroll
        for (int l = 0; l < 4; ++l) {
            float xs = (l == 0) ? xv.x : (l == 1) ? xv.y : (l == 2) ? xv.z : xv.w;
            const float4* wr = &Ws[(kk * 4 + l) * 16];
#pragma unroll
            for (int j = 0; j < 16; ++j) {
                float4 w = wr[j];
                acc[j].x += xs * w.x; acc[j].y += xs * w.y;
                acc[j].z += xs * w.z; acc[j].w += xs * w.w;
            }
        }
    }
    float dv = dinv[r];
    __half hv[64];
#pragma unroll
    for (int j = 0; j < 16; ++j) {
        hv[4 * j + 0] = __float2half_rn(acc[j].x * dv);
        hv[4 * j + 1] = __float2half_rn(acc[j].y * dv);
        hv[4 * j + 2] = __float2half_rn(acc[j].z * dv);
        hv[4 * j + 3] = __float2half_rn(acc[j].w * dv);
    }
    uint4* out = (uint4*)(hsA + (size_t)r * HID);
#pragma unroll
    for (int j = 0; j < 8; ++j) out[j] = ((uint4*)hv)[j];
}

// hsA[r,:] = half((relu(z[r,:]*sc+sh) @ W2) * dinv[r])
__global__ __launch_bounds__(256) void k_gemm2(const float* __restrict__ z,
                                               const float* __restrict__ W,
                                               const float* __restrict__ scsh,
                                               const float* __restrict__ dinv,
                                               __half* __restrict__ hsA, int n) {
    __shared__ float4 Ws[HID * HID / 4];    // 16 KB
    __shared__ float sc[64], sh[64];
    int t = threadIdx.x;
    const float4* W4 = (const float4*)W;
#pragma unroll
    for (int i = 0; i < 4; ++i) Ws[t + i * 256] = W4[t + i * 256];
    if (t < 64) { sc[t] = scsh[t]; sh[t] = scsh[64 + t]; }
    __syncthreads();
    int r = blockIdx.x * 256 + t;
    if (r >= n) return;
    float4 acc[16];
#pragma unroll
    for (int j = 0; j < 16; ++j) acc[j] = make_float4(0.f, 0.f, 0.f, 0.f);
    const float4* zr = (const float4*)(z + (size_t)r * HID);
    for (int kk = 0; kk < 16; ++kk) {
        float4 zv = zr[kk];
#pragma unroll
        for (int l = 0; l < 4; ++l) {
            int k = kk * 4 + l;
            float zs = (l == 0) ? zv.x : (l == 1) ? zv.y : (l == 2) ? zv.z : zv.w;
            float a = fmaxf(0.f, zs * sc[k] + sh[k]);
            const float4* wr = &Ws[k * 16];
#pragma unroll
            for (int j = 0; j < 16; ++j) {
                float4 w = wr[j];
                acc[j].x += a * w.x; acc[j].y += a * w.y;
                acc[j].z += a * w.z; acc[j].w += a * w.w;
            }
        }
    }
    float dv = dinv[r];
    __half hv[64];
#pragma unroll
    for (int j = 0; j < 16; ++j) {
        hv[4 * j + 0] = __float2half_rn(acc[j].x * dv);
        hv[4 * j + 1] = __float2half_rn(acc[j].y * dv);
        hv[4 * j + 2] = __float2half_rn(acc[j].z * dv);
        hv[4 * j + 3] = __float2half_rn(acc[j].w * dv);
    }
    uint4* out = (uint4*)(hsA + (size_t)r * HID);
#pragma unroll
    for (int j = 0; j < 8; ++j) out[j] = ((uint4*)hv)[j];
}

__global__ __launch_bounds__(256) void k_gemm3(const float* __restrict__ z,
                                               const float* __restrict__ W,
                                               const float* __restrict__ scsh,
                                               const float* __restrict__ dinv,
                                               float* __restrict__ hs3, int n) {
    __shared__ float4 Ws[64];
    __shared__ float sc[64], sh[64];
    int t = threadIdx.x;
    if (t < 64) { Ws[t] = ((const float4*)W)[t]; sc[t] = scsh[t]; sh[t] = scsh[64 + t]; }
    __syncthreads();
    int r = blockIdx.x * 256 + t;
    if (r >= n) return;
    float4 acc = make_float4(0.f, 0.f, 0.f, 0.f);
    const float4* zr = (const float4*)(z + (size_t)r * HID);
    for (int kk = 0; kk < 16; ++kk) {
        float4 zv = zr[kk];
#pragma unroll
        for (int l = 0; l < 4; ++l) {
            int k = kk * 4 + l;
            float zs = (l == 0) ? zv.x : (l == 1) ? zv.y : (l == 2) ? zv.z : zv.w;
            float a = fmaxf(0.f, zs * sc[k] + sh[k]);
            float4 w = Ws[k];
            acc.x += a * w.x; acc.y += a * w.y; acc.z += a * w.z; acc.w += a * w.w;
        }
    }
    float dv = dinv[r];
    ((float4*)hs3)[r] = make_float4(acc.x * dv, acc.y * dv, acc.z * dv, acc.w * dv);
}

// ---------------- Aggregation (CSR gather, fp16 source) ----------------

__device__ inline float4 h4tof(uint2 r) {
    __half2 a = *reinterpret_cast<__half2*>(&r.x);
    __half2 b = *reinterpret_cast<__half2*>(&r.y);
    float2 fa = __half22float2(a), fb = __half22float2(b);
    return make_float4(fa.x, fa.y, fb.x, fb.y);
}

// z[i,:] = dinv[i] * (hsA[i,:] + sum_{s in nbr(i)} hsA[s,:]) + bias
// 16 lanes per node; each lane owns channel quad c4 (8B fp16 load / edge).
__global__ __launch_bounds__(256) void k_agg64(const __half* __restrict__ hsA,
                                               const int* __restrict__ rowptr,
                                               const int* __restrict__ csr,
                                               const float* __restrict__ dinv,
                                               const float* __restrict__ bias,
                                               float* __restrict__ z,
                                               float* __restrict__ sums,
                                               float* __restrict__ sumsq, int n) {
    __shared__ float lsum[64], lsq[64];
    int t = threadIdx.x;
    if (t < 64) { lsum[t] = 0.f; lsq[t] = 0.f; }
    __syncthreads();
    const uint2* h2 = (const uint2*)hsA;        // row = 16 uint2 (64 halves)
    long long total = (long long)n * 16;
    int stride = gridDim.x * blockDim.x;        // multiple of 16 -> c4 invariant
    int gid = blockIdx.x * blockDim.x + t;
    int c4 = gid & 15;
    float4 bv = ((const float4*)bias)[c4];
    float ps0 = 0.f, ps1 = 0.f, ps2 = 0.f, ps3 = 0.f;
    float pq0 = 0.f, pq1 = 0.f, pq2 = 0.f, pq3 = 0.f;
    for (long long w = gid; w < total; w += stride) {
        int i = (int)(w >> 4);
        float4 a0 = h4tof(h2[(size_t)i * 16 + c4]);   // self-loop term
        float4 a1 = make_float4(0.f, 0.f, 0.f, 0.f);
        float4 a2 = make_float4(0.f, 0.f, 0.f, 0.f);
        float4 a3 = make_float4(0.f, 0.f, 0.f, 0.f);
        int beg = rowptr[i], end = rowptr[i + 1];
        int j = beg;
        for (; j + 4 <= end; j += 4) {
            int s0 = csr[j], s1 = csr[j + 1], s2 = csr[j + 2], s3 = csr[j + 3];
            float4 v0 = h4tof(h2[(size_t)s0 * 16 + c4]);
            float4 v1 = h4tof(h2[(size_t)s1 * 16 + c4]);
            float4 v2 = h4tof(h2[(size_t)s2 * 16 + c4]);
            float4 v3 = h4tof(h2[(size_t)s3 * 16 + c4]);
            a0.x += v0.x; a0.y += v0.y; a0.z += v0.z; a0.w += v0.w;
            a1.x += v1.x; a1.y += v1.y; a1.z += v1.z; a1.w += v1.w;
            a2.x += v2.x; a2.y += v2.y; a2.z += v2.z; a2.w += v2.w;
            a3.x += v3.x; a3.y += v3.y; a3.z += v3.z; a3.w += v3.w;
        }
        for (; j < end; ++j) {
            float4 v = h4tof(h2[(size_t)csr[j] * 16 + c4]);
            a0.x += v.x; a0.y += v.y; a0.z += v.z; a0.w += v.w;
        }
        float4 acc = make_float4((a0.x + a1.x) + (a2.x + a3.x),
                                 (a0.y + a1.y) + (a2.y + a3.y),
                                 (a0.z + a1.z) + (a2.z + a3.z),
                                 (a0.w + a1.w) + (a2.w + a3.w));
        float dv = dinv[i];
        float4 zv = make_float4(acc.x * dv + bv.x, acc.y * dv + bv.y,
                                acc.z * dv + bv.z, acc.w * dv + bv.w);
        ((float4*)z)[(size_t)i * 16 + c4] = zv;
        ps0 += zv.x; ps1 += zv.y; ps2 += zv.z; ps3 += zv.w;
        pq0 += zv.x * zv.x; pq1 += zv.y * zv.y; pq2 += zv.z * zv.z; pq3 += zv.w * zv.w;
    }
    int cb = c4 * 4;
    atomicAdd(&lsum[cb + 0], ps0); atomicAdd(&lsum[cb + 1], ps1);
    atomicAdd(&lsum[cb + 2], ps2); atomicAdd(&lsum[cb + 3], ps3);
    atomicAdd(&lsq[cb + 0], pq0);  atomicAdd(&lsq[cb + 1], pq1);
    atomicAdd(&lsq[cb + 2], pq2);  atomicAdd(&lsq[cb + 3], pq3);
    __syncthreads();
    if (t < 64) { atomicAdd(&sums[t], lsum[t]); atomicAdd(&sumsq[t], lsq[t]); }
}

__global__ void k_agg4(const float* __restrict__ hs3, const int* __restrict__ rowptr,
                       const int* __restrict__ csr, const float* __restrict__ dinv,
                       const float* __restrict__ b3, float* __restrict__ out, int n) {
    int i = blockIdx.x * blockDim.x + threadIdx.x;
    if (i >= n) return;
    const float4* h4 = (const float4*)hs3;
    float4 a0 = h4[i];
    float4 a1 = make_float4(0.f, 0.f, 0.f, 0.f);
    float4 a2 = make_float4(0.f, 0.f, 0.f, 0.f);
    float4 a3 = make_float4(0.f, 0.f, 0.f, 0.f);
    int beg = rowptr[i], end = rowptr[i + 1];
    int j = beg;
    for (; j + 4 <= end; j += 4) {
        int s0 = csr[j], s1 = csr[j + 1], s2 = csr[j + 2], s3 = csr[j + 3];
        float4 v0 = h4[s0], v1 = h4[s1], v2 = h4[s2], v3 = h4[s3];
        a0.x += v0.x; a0.y += v0.y; a0.z += v0.z; a0.w += v0.w;
        a1.x += v1.x; a1.y += v1.y; a1.z += v1.z; a1.w += v1.w;
        a2.x += v2.x; a2.y += v2.y; a2.z += v2.z; a2.w += v2.w;
        a3.x += v3.x; a3.y += v3.y; a3.z += v3.z; a3.w += v3.w;
    }
    for (; j < end; ++j) {
        float4 v = h4[csr[j]];
        a0.x += v.x; a0.y += v.y; a0.z += v.z; a0.w += v.w;
    }
    float4 acc = make_float4((a0.x + a1.x) + (a2.x + a3.x),
                             (a0.y + a1.y) + (a2.y + a3.y),
                             (a0.z + a1.z) + (a2.z + a3.z),
                             (a0.w + a1.w) + (a2.w + a3.w));
    float dv = dinv[i];
    float4 bv = *(const float4*)b3;
    ((float4*)out)[i] = make_float4(acc.x * dv + bv.x, acc.y * dv + bv.y,
                                    acc.z * dv + bv.z, acc.w * dv + bv.w);
}

__global__ void k_bnstats(const float* __restrict__ sums, const float* __restrict__ sumsq,
                          const float* __restrict__ g, const float* __restrict__ be,
                          float* __restrict__ scsh, int n) {
    int t = threadIdx.x;
    if (t < 64) {
        float inv_n = 1.f / (float)n;
        float m = sums[t] * inv_n;
        float v = sumsq[t] * inv_n - m * m;
        float sc = g[t] / sqrtf(v + BN_EPS);
        scsh[t] = sc;
        scsh[64 + t] = be[t] - m * sc;
    }
}

// ---------------- launch ----------------

extern "C" void kernel_launch(void* const* d_in, const int* in_sizes, int n_in,
                              void* d_out, int out_size, void* d_ws, size_t ws_size,
                              hipStream_t stream) {
    const float* x   = (const float*)d_in[0];
    const int*   ei  = (const int*)d_in[1];
    const float* W1  = (const float*)d_in[2];
    const float* b1  = (const float*)d_in[3];
    const float* g1  = (const float*)d_in[4];
    const float* be1 = (const float*)d_in[5];
    const float* W2  = (const float*)d_in[6];
    const float* b2  = (const float*)d_in[7];
    const float* g2  = (const float*)d_in[8];
    const float* be2 = (const float*)d_in[9];
    const float* W3  = (const float*)d_in[10];
    const float* b3  = (const float*)d_in[11];

    int n = in_sizes[0] / IN_F;
    int e = in_sizes[1] / 2;
    const int* src = ei;
    const int* dst = ei + e;

    float* wsf = (float*)d_ws;
    size_t NP = ((size_t)(n + 256) + 255) & ~(size_t)255;
    size_t EP = ((size_t)e + 255) & ~(size_t)255;
    size_t NB = (((size_t)n * HID) + 255) & ~(size_t)255;

    int*   degi   = (int*)wsf;
    float* dinv   = wsf + NP;
    int*   rowptr = (int*)(wsf + 2 * NP);
    int*   cursor = (int*)(wsf + 3 * NP);
    float* stats  = wsf + 4 * NP;          // 256
    float* scsh   = stats + 256;           // 256
    int*   part   = (int*)(scsh + 256);    // 1024
    int*   bhist  = part + 1024;           // 512
    int*   boff   = bhist + 512;           // 520
    int*   bcur   = boff + 520;            // 512
    int*   csr    = bcur + 512;
    float* A      = (float*)csr + EP;      // staged features: used as __half [n,64]
    float* B      = A + NB;                // z buffer fp32 [n,64]
    float* hs3    = B + NB;                // [n,4]
    uint2* pairs  = (uint2*)B;             // alias: B first written after fill2 reads
    __half* Ah    = (__half*)A;

    int nb = (n + 255) / 256;
    int eb = (e + CHUNK - 1) / CHUNK;      // chunked edge blocks
    int sb = (n + 1023) / 1024;
    int nbkt = (n + 255) >> BSH;           // buckets

    k_init <<<nb, 256, 0, stream>>>(degi, stats, bhist, n);
    k_count<<<eb, 256, 0, stream>>>(dst, degi, bhist, e);
    k_scan1<<<sb, 256, 0, stream>>>(degi, part, n);
    k_scan2<<<1, 1024, 0, stream>>>(part, sb);
    k_scan3<<<sb, 256, 0, stream>>>(degi, part, rowptr, cursor, dinv, n, e);
    k_bscan<<<1, 512, 0, stream>>>(bhist, boff, bcur, nbkt, e);
    k_bin  <<<eb, 256, 0, stream>>>(src, dst, bcur, pairs, e);
    k_fill2<<<nbkt, 256, 0, stream>>>(pairs, boff, cursor, csr);

    // layer 1
    k_gemm1<<<nb, 256, 0, stream>>>(x, W1, dinv, Ah, n);
    k_agg64<<<2048, 256, 0, stream>>>(Ah, rowptr, csr, dinv, b1, B, stats, stats + 64, n);
    k_bnstats<<<1, 64, 0, stream>>>(stats, stats + 64, g1, be1, scsh, n);

    // layer 2
    k_gemm2<<<nb, 256, 0, stream>>>(B, W2, scsh, dinv, Ah, n);
    k_agg64<<<2048, 256, 0, stream>>>(Ah, rowptr, csr, dinv, b2, B, stats + 128, stats + 192, n);
    k_bnstats<<<1, 64, 0, stream>>>(stats + 128, stats + 192, g2, be2, scsh + 128, n);

    // layer 3
    k_gemm3<<<nb, 256, 0, stream>>>(B, W3, scsh + 128, dinv, hs3, n);
    k_agg4 <<<nb, 256, 0, stream>>>(hs3, rowptr, csr, dinv, b3, (float*)d_out, n);
}

// Round 6
// 348.487 us; speedup vs baseline: 1.4255x; 1.2290x over previous
//
#include <hip/hip_runtime.h>
#include <hip/hip_fp16.h>

#define IN_F 128
#define HID 64
#define NCLS 4
#define BN_EPS 1e-5f

#define MAXB 512        // max buckets (n <= 131072)
#define BSH 8           // bucket = dst >> 8  (256 nodes per bucket)
#define CHUNK 4096      // edges per block in chunked passes

// ---------------- CSR build ----------------

__global__ void k_init(float* __restrict__ stats, int* __restrict__ bhist) {
    int i = blockIdx.x * blockDim.x + threadIdx.x;
    if (i < 256) stats[i] = 0.f;
    if (i < MAXB) bhist[i] = 0;
}

// per-bucket histogram only (chunked, LDS-staged flush)
__global__ __launch_bounds__(256) void k_hist(const int* __restrict__ dst,
                                              int* __restrict__ bhist, int e) {
    __shared__ int lh[MAXB];
    int t = threadIdx.x;
    for (int i = t; i < MAXB; i += 256) lh[i] = 0;
    __syncthreads();
    int base = blockIdx.x * CHUNK;
    int m = min(CHUNK, e - base);
    for (int i = t; i < m; i += 256) atomicAdd(&lh[dst[base + i] >> BSH], 1);
    __syncthreads();
    for (int b = t; b < MAXB; b += 256) { int c = lh[b]; if (c) atomicAdd(&bhist[b], c); }
}

// exclusive scan of bucket histogram -> boff, bcur; also rowptr[n] = e
__global__ __launch_bounds__(512) void k_bscan(const int* __restrict__ bhist,
                                               int* __restrict__ boff,
                                               int* __restrict__ bcur,
                                               int* __restrict__ rowptr,
                                               int nbkt, int n, int e) {
    __shared__ int sh[512];
    int t = threadIdx.x;
    int v = (t < nbkt) ? bhist[t] : 0;
    sh[t] = v; __syncthreads();
    for (int off = 1; off < 512; off <<= 1) {
        int add = (t >= off) ? sh[t - off] : 0;
        __syncthreads();
        sh[t] += add;
        __syncthreads();
    }
    if (t < nbkt) { int ex = sh[t] - v; boff[t] = ex; bcur[t] = ex; }
    if (t == 0) { boff[nbkt] = e; rowptr[n] = e; }
}

// phase A: bin packed (src<<8 | dst&255) by dst-bucket, LDS multisplit, coalesced writes
__global__ __launch_bounds__(256) void k_bin(const int* __restrict__ src,
                                             const int* __restrict__ dst,
                                             int* __restrict__ bcur,
                                             unsigned* __restrict__ pairs, int e) {
    __shared__ uint2 stage[CHUNK];
    __shared__ int cnt[MAXB], off[MAXB], gbase[MAXB];
    int t = threadIdx.x;
    for (int i = t; i < MAXB; i += 256) cnt[i] = 0;
    __syncthreads();
    int base = blockIdx.x * CHUNK;
    int m = min(CHUNK, e - base);
    int lr[CHUNK / 256];
#pragma unroll
    for (int j = 0; j < CHUNK / 256; ++j) {
        int i = t + j * 256;
        if (i < m) lr[j] = atomicAdd(&cnt[dst[base + i] >> BSH], 1);
    }
    __syncthreads();
    // inclusive scan of cnt (512 entries, 256 threads, Hillis-Steele, 2/thread)
    off[t] = cnt[t]; off[t + 256] = cnt[t + 256];
    __syncthreads();
    for (int o = 1; o < 512; o <<= 1) {
        int v0 = (t >= o) ? off[t - o] : 0;
        int v1 = (t + 256 >= o) ? off[t + 256 - o] : 0;
        __syncthreads();
        off[t] += v0; off[t + 256] += v1;
        __syncthreads();
    }
    // reserve global range; bias so global addr = gbase[b] + stage_index
    for (int b = t; b < MAXB; b += 256) {
        int c = cnt[b];
        int ex = off[b] - c;                       // exclusive local offset
        gbase[b] = c ? (atomicAdd(&bcur[b], c) - ex) : 0;
    }
    __syncthreads();
#pragma unroll
    for (int j = 0; j < CHUNK / 256; ++j) {
        int i = t + j * 256;
        if (i < m) {
            int s = src[base + i], d = dst[base + i];
            int b = d >> BSH;
            stage[(off[b] - cnt[b]) + lr[j]] = make_uint2((unsigned)s, (unsigned)d);
        }
    }
    __syncthreads();
    for (int i = t; i < m; i += 256) {
        uint2 p = stage[i];
        int b = (int)(p.y >> BSH);
        pairs[gbase[b] + i] = (p.x << 8) | (p.y & 255u);
    }
}

// phase B: per-bucket (256 nodes) LDS degree-count + scan -> rowptr/dinv, then
// LDS-cursor scatter into csr. Replaces global degi atomics + 3 scan kernels.
__global__ __launch_bounds__(256) void k_bucket(const unsigned* __restrict__ pairs,
                                                const int* __restrict__ boff,
                                                int* __restrict__ rowptr,
                                                float* __restrict__ dinv,
                                                int* __restrict__ csr, int n) {
    __shared__ int deg[256], loff[256], cur[256];
    int b = blockIdx.x, t = threadIdx.x;
    deg[t] = 0;
    __syncthreads();
    int beg = boff[b], end = boff[b + 1];
    for (int i = beg + t; i < end; i += 256)
        atomicAdd(&deg[pairs[i] & 255u], 1);
    __syncthreads();
    int v = deg[t];
    loff[t] = v;
    __syncthreads();
    for (int o = 1; o < 256; o <<= 1) {
        int add = (t >= o) ? loff[t - o] : 0;
        __syncthreads();
        loff[t] += add;
        __syncthreads();
    }
    int ex = loff[t] - v;                 // exclusive in-bucket offset
    int node = b * 256 + t;
    if (node < n) {
        rowptr[node] = beg + ex;
        dinv[node] = 1.0f / sqrtf((float)(v + 1));   // deg includes self-loop
    }
    cur[t] = beg + ex;
    __syncthreads();
    for (int i = beg + t; i < end; i += 256) {
        unsigned p = pairs[i];
        int pos = atomicAdd(&cur[p & 255u], 1);
        csr[pos] = (int)(p >> 8);
    }
}

// ---------------- GEMMs (thread-per-row, W in LDS; fp16 staged output) ----------------

// hsA[r,:] = half((x[r,:] @ W1) * dinv[r])
__global__ __launch_bounds__(256) void k_gemm1(const float* __restrict__ x,
                                               const float* __restrict__ W,
                                               const float* __restrict__ dinv,
                                               __half* __restrict__ hsA, int n) {
    __shared__ float4 Ws[IN_F * HID / 4];   // 32 KB
    int t = threadIdx.x;
    const float4* W4 = (const float4*)W;
#pragma unroll
    for (int i = 0; i < 8; ++i) Ws[t + i * 256] = W4[t + i * 256];
    __syncthreads();
    int r = blockIdx.x * 256 + t;
    if (r >= n) return;
    float4 acc[16];
#pragma unroll
    for (int j = 0; j < 16; ++j) acc[j] = make_float4(0.f, 0.f, 0.f, 0.f);
    const float4* xr = (const float4*)(x + (size_t)r * IN_F);
    for (int kk = 0; kk < 32; ++kk) {
        float4 xv = xr[kk];
#pragma unroll
        for (int l = 0; l < 4; ++l) {
            float xs = (l == 0) ? xv.x : (l == 1) ? xv.y : (l == 2) ? xv.z : xv.w;
            const float4* wr = &Ws[(kk * 4 + l) * 16];
#pragma unroll
            for (int j = 0; j < 16; ++j) {
                float4 w = wr[j];
                acc[j].x += xs * w.x; acc[j].y += xs * w.y;
                acc[j].z += xs * w.z; acc[j].w += xs * w.w;
            }
        }
    }
    float dv = dinv[r];
    __half hv[64];
#pragma unroll
    for (int j = 0; j < 16; ++j) {
        hv[4 * j + 0] = __float2half_rn(acc[j].x * dv);
        hv[4 * j + 1] = __float2half_rn(acc[j].y * dv);
        hv[4 * j + 2] = __float2half_rn(acc[j].z * dv);
        hv[4 * j + 3] = __float2half_rn(acc[j].w * dv);
    }
    uint4* out = (uint4*)(hsA + (size_t)r * HID);
#pragma unroll
    for (int j = 0; j < 8; ++j) out[j] = ((uint4*)hv)[j];
}

// hsA[r,:] = half((relu(z[r,:]*sc+sh) @ W2) * dinv[r])
__global__ __launch_bounds__(256) void k_gemm2(const float* __restrict__ z,
                                               const float* __restrict__ W,
                                               const float* __restrict__ scsh,
                                               const float* __restrict__ dinv,
                                               __half* __restrict__ hsA, int n) {
    __shared__ float4 Ws[HID * HID / 4];    // 16 KB
    __shared__ float sc[64], sh[64];
    int t = threadIdx.x;
    const float4* W4 = (const float4*)W;
#pragma unroll
    for (int i = 0; i < 4; ++i) Ws[t + i * 256] = W4[t + i * 256];
    if (t < 64) { sc[t] = scsh[t]; sh[t] = scsh[64 + t]; }
    __syncthreads();
    int r = blockIdx.x * 256 + t;
    if (r >= n) return;
    float4 acc[16];
#pragma unroll
    for (int j = 0; j < 16; ++j) acc[j] = make_float4(0.f, 0.f, 0.f, 0.f);
    const float4* zr = (const float4*)(z + (size_t)r * HID);
    for (int kk = 0; kk < 16; ++kk) {
        float4 zv = zr[kk];
#pragma unroll
        for (int l = 0; l < 4; ++l) {
            int k = kk * 4 + l;
            float zs = (l == 0) ? zv.x : (l == 1) ? zv.y : (l == 2) ? zv.z : zv.w;
            float a = fmaxf(0.f, zs * sc[k] + sh[k]);
            const float4* wr = &Ws[k * 16];
#pragma unroll
            for (int j = 0; j < 16; ++j) {
                float4 w = wr[j];
                acc[j].x += a * w.x; acc[j].y += a * w.y;
                acc[j].z += a * w.z; acc[j].w += a * w.w;
            }
        }
    }
    float dv = dinv[r];
    __half hv[64];
#pragma unroll
    for (int j = 0; j < 16; ++j) {
        hv[4 * j + 0] = __float2half_rn(acc[j].x * dv);
        hv[4 * j + 1] = __float2half_rn(acc[j].y * dv);
        hv[4 * j + 2] = __float2half_rn(acc[j].z * dv);
        hv[4 * j + 3] = __float2half_rn(acc[j].w * dv);
    }
    uint4* out = (uint4*)(hsA + (size_t)r * HID);
#pragma unroll
    for (int j = 0; j < 8; ++j) out[j] = ((uint4*)hv)[j];
}

__global__ __launch_bounds__(256) void k_gemm3(const float* __restrict__ z,
                                               const float* __restrict__ W,
                                               const float* __restrict__ scsh,
                                               const float* __restrict__ dinv,
                                               float* __restrict__ hs3, int n) {
    __shared__ float4 Ws[64];
    __shared__ float sc[64], sh[64];
    int t = threadIdx.x;
    if (t < 64) { Ws[t] = ((const float4*)W)[t]; sc[t] = scsh[t]; sh[t] = scsh[64 + t]; }
    __syncthreads();
    int r = blockIdx.x * 256 + t;
    if (r >= n) return;
    float4 acc = make_float4(0.f, 0.f, 0.f, 0.f);
    const float4* zr = (const float4*)(z + (size_t)r * HID);
    for (int kk = 0; kk < 16; ++kk) {
        float4 zv = zr[kk];
#pragma unroll
        for (int l = 0; l < 4; ++l) {
            int k = kk * 4 + l;
            float zs = (l == 0) ? zv.x : (l == 1) ? zv.y : (l == 2) ? zv.z : zv.w;
            float a = fmaxf(0.f, zs * sc[k] + sh[k]);
            float4 w = Ws[k];
            acc.x += a * w.x; acc.y += a * w.y; acc.z += a * w.z; acc.w += a * w.w;
        }
    }
    float dv = dinv[r];
    ((float4*)hs3)[r] = make_float4(acc.x * dv, acc.y * dv, acc.z * dv, acc.w * dv);
}

// ---------------- Aggregation (CSR gather, fp16 source) ----------------

__device__ inline float4 h4tof(uint2 r) {
    __half2 a = *reinterpret_cast<__half2*>(&r.x);
    __half2 b = *reinterpret_cast<__half2*>(&r.y);
    float2 fa = __half22float2(a), fb = __half22float2(b);
    return make_float4(fa.x, fa.y, fb.x, fb.y);
}

// z[i,:] = dinv[i] * (hsA[i,:] + sum_{s in nbr(i)} hsA[s,:]) + bias
// 16 lanes per node; each lane owns channel quad c4 (8B fp16 load / edge).
__global__ __launch_bounds__(256) void k_agg64(const __half* __restrict__ hsA,
                                               const int* __restrict__ rowptr,
                                               const int* __restrict__ csr,
                                               const float* __restrict__ dinv,
                                               const float* __restrict__ bias,
                                               float* __restrict__ z,
                                               float* __restrict__ sums,
                                               float* __restrict__ sumsq, int n) {
    __shared__ float lsum[64], lsq[64];
    int t = threadIdx.x;
    if (t < 64) { lsum[t] = 0.f; lsq[t] = 0.f; }
    __syncthreads();
    const uint2* h2 = (const uint2*)hsA;        // row = 16 uint2 (64 halves)
    long long total = (long long)n * 16;
    int stride = gridDim.x * blockDim.x;        // multiple of 16 -> c4 invariant
    int gid = blockIdx.x * blockDim.x + t;
    int c4 = gid & 15;
    float4 bv = ((const float4*)bias)[c4];
    float ps0 = 0.f, ps1 = 0.f, ps2 = 0.f, ps3 = 0.f;
    float pq0 = 0.f, pq1 = 0.f, pq2 = 0.f, pq3 = 0.f;
    for (long long w = gid; w < total; w += stride) {
        int i = (int)(w >> 4);
        float4 a0 = h4tof(h2[(size_t)i * 16 + c4]);   // self-loop term
        float4 a1 = make_float4(0.f, 0.f, 0.f, 0.f);
        float4 a2 = make_float4(0.f, 0.f, 0.f, 0.f);
        float4 a3 = make_float4(0.f, 0.f, 0.f, 0.f);
        int beg = rowptr[i], end = rowptr[i + 1];
        int j = beg;
        for (; j + 4 <= end; j += 4) {
            int s0 = csr[j], s1 = csr[j + 1], s2 = csr[j + 2], s3 = csr[j + 3];
            float4 v0 = h4tof(h2[(size_t)s0 * 16 + c4]);
            float4 v1 = h4tof(h2[(size_t)s1 * 16 + c4]);
            float4 v2 = h4tof(h2[(size_t)s2 * 16 + c4]);
            float4 v3 = h4tof(h2[(size_t)s3 * 16 + c4]);
            a0.x += v0.x; a0.y += v0.y; a0.z += v0.z; a0.w += v0.w;
            a1.x += v1.x; a1.y += v1.y; a1.z += v1.z; a1.w += v1.w;
            a2.x += v2.x; a2.y += v2.y; a2.z += v2.z; a2.w += v2.w;
            a3.x += v3.x; a3.y += v3.y; a3.z += v3.z; a3.w += v3.w;
        }
        for (; j < end; ++j) {
            float4 v = h4tof(h2[(size_t)csr[j] * 16 + c4]);
            a0.x += v.x; a0.y += v.y; a0.z += v.z; a0.w += v.w;
        }
        float4 acc = make_float4((a0.x + a1.x) + (a2.x + a3.x),
                                 (a0.y + a1.y) + (a2.y + a3.y),
                                 (a0.z + a1.z) + (a2.z + a3.z),
                                 (a0.w + a1.w) + (a2.w + a3.w));
        float dv = dinv[i];
        float4 zv = make_float4(acc.x * dv + bv.x, acc.y * dv + bv.y,
                                acc.z * dv + bv.z, acc.w * dv + bv.w);
        ((float4*)z)[(size_t)i * 16 + c4] = zv;
        ps0 += zv.x; ps1 += zv.y; ps2 += zv.z; ps3 += zv.w;
        pq0 += zv.x * zv.x; pq1 += zv.y * zv.y; pq2 += zv.z * zv.z; pq3 += zv.w * zv.w;
    }
    int cb = c4 * 4;
    atomicAdd(&lsum[cb + 0], ps0); atomicAdd(&lsum[cb + 1], ps1);
    atomicAdd(&lsum[cb + 2], ps2); atomicAdd(&lsum[cb + 3], ps3);
    atomicAdd(&lsq[cb + 0], pq0);  atomicAdd(&lsq[cb + 1], pq1);
    atomicAdd(&lsq[cb + 2], pq2);  atomicAdd(&lsq[cb + 3], pq3);
    __syncthreads();
    if (t < 64) { atomicAdd(&sums[t], lsum[t]); atomicAdd(&sumsq[t], lsq[t]); }
}

__global__ void k_agg4(const float* __restrict__ hs3, const int* __restrict__ rowptr,
                       const int* __restrict__ csr, const float* __restrict__ dinv,
                       const float* __restrict__ b3, float* __restrict__ out, int n) {
    int i = blockIdx.x * blockDim.x + threadIdx.x;
    if (i >= n) return;
    const float4* h4 = (const float4*)hs3;
    float4 a0 = h4[i];
    float4 a1 = make_float4(0.f, 0.f, 0.f, 0.f);
    float4 a2 = make_float4(0.f, 0.f, 0.f, 0.f);
    float4 a3 = make_float4(0.f, 0.f, 0.f, 0.f);
    int beg = rowptr[i], end = rowptr[i + 1];
    int j = beg;
    for (; j + 4 <= end; j += 4) {
        int s0 = csr[j], s1 = csr[j + 1], s2 = csr[j + 2], s3 = csr[j + 3];
        float4 v0 = h4[s0], v1 = h4[s1], v2 = h4[s2], v3 = h4[s3];
        a0.x += v0.x; a0.y += v0.y; a0.z += v0.z; a0.w += v0.w;
        a1.x += v1.x; a1.y += v1.y; a1.z += v1.z; a1.w += v1.w;
        a2.x += v2.x; a2.y += v2.y; a2.z += v2.z; a2.w += v2.w;
        a3.x += v3.x; a3.y += v3.y; a3.z += v3.z; a3.w += v3.w;
    }
    for (; j < end; ++j) {
        float4 v = h4[csr[j]];
        a0.x += v.x; a0.y += v.y; a0.z += v.z; a0.w += v.w;
    }
    float4 acc = make_float4((a0.x + a1.x) + (a2.x + a3.x),
                             (a0.y + a1.y) + (a2.y + a3.y),
                             (a0.z + a1.z) + (a2.z + a3.z),
                             (a0.w + a1.w) + (a2.w + a3.w));
    float dv = dinv[i];
    float4 bv = *(const float4*)b3;
    ((float4*)out)[i] = make_float4(acc.x * dv + bv.x, acc.y * dv + bv.y,
                                    acc.z * dv + bv.z, acc.w * dv + bv.w);
}

__global__ void k_bnstats(const float* __restrict__ sums, const float* __restrict__ sumsq,
                          const float* __restrict__ g, const float* __restrict__ be,
                          float* __restrict__ scsh, int n) {
    int t = threadIdx.x;
    if (t < 64) {
        float inv_n = 1.f / (float)n;
        float m = sums[t] * inv_n;
        float v = sumsq[t] * inv_n - m * m;
        float sc = g[t] / sqrtf(v + BN_EPS);
        scsh[t] = sc;
        scsh[64 + t] = be[t] - m * sc;
    }
}

// ---------------- launch ----------------

extern "C" void kernel_launch(void* const* d_in, const int* in_sizes, int n_in,
                              void* d_out, int out_size, void* d_ws, size_t ws_size,
                              hipStream_t stream) {
    const float* x   = (const float*)d_in[0];
    const int*   ei  = (const int*)d_in[1];
    const float* W1  = (const float*)d_in[2];
    const float* b1  = (const float*)d_in[3];
    const float* g1  = (const float*)d_in[4];
    const float* be1 = (const float*)d_in[5];
    const float* W2  = (const float*)d_in[6];
    const float* b2  = (const float*)d_in[7];
    const float* g2  = (const float*)d_in[8];
    const float* be2 = (const float*)d_in[9];
    const float* W3  = (const float*)d_in[10];
    const float* b3  = (const float*)d_in[11];

    int n = in_sizes[0] / IN_F;
    int e = in_sizes[1] / 2;
    const int* src = ei;
    const int* dst = ei + e;

    float* wsf = (float*)d_ws;
    size_t NP = ((size_t)(n + 256) + 255) & ~(size_t)255;   // >= n+1
    size_t EP = ((size_t)e + 255) & ~(size_t)255;
    size_t NB = (((size_t)n * HID) + 255) & ~(size_t)255;

    float* stats  = wsf;                   // 256
    float* scsh   = wsf + 256;             // 256
    int*   bhist  = (int*)(wsf + 512);     // 512
    int*   boff   = bhist + 512;           // 520
    int*   bcur   = boff + 520;            // 512
    int*   rowptr = bcur + 512;            // NP ints
    float* dinv   = (float*)(rowptr + NP); // NP floats
    int*   csr    = (int*)(dinv + NP);     // EP ints
    float* A      = (float*)(csr + EP);    // staged features: used as __half [n,64]
    float* B      = A + NB;                // z buffer fp32 [n,64]
    float* hs3    = B + NB;                // [n,4]
    unsigned* pairs = (unsigned*)B;        // alias: B first written after k_bucket
    __half* Ah    = (__half*)A;

    int nb = (n + 255) / 256;
    int eb = (e + CHUNK - 1) / CHUNK;      // chunked edge blocks
    int nbkt = (n + 255) >> BSH;           // buckets (<= MAXB)

    k_init  <<<2, 256, 0, stream>>>(stats, bhist);
    k_hist  <<<eb, 256, 0, stream>>>(dst, bhist, e);
    k_bscan <<<1, 512, 0, stream>>>(bhist, boff, bcur, rowptr, nbkt, n, e);
    k_bin   <<<eb, 256, 0, stream>>>(src, dst, bcur, pairs, e);
    k_bucket<<<nbkt, 256, 0, stream>>>(pairs, boff, rowptr, dinv, csr, n);

    // layer 1
    k_gemm1<<<nb, 256, 0, stream>>>(x, W1, dinv, Ah, n);
    k_agg64<<<2048, 256, 0, stream>>>(Ah, rowptr, csr, dinv, b1, B, stats, stats + 64, n);
    k_bnstats<<<1, 64, 0, stream>>>(stats, stats + 64, g1, be1, scsh, n);

    // layer 2
    k_gemm2<<<nb, 256, 0, stream>>>(B, W2, scsh, dinv, Ah, n);
    k_agg64<<<2048, 256, 0, stream>>>(Ah, rowptr, csr, dinv, b2, B, stats + 128, stats + 192, n);
    k_bnstats<<<1, 64, 0, stream>>>(stats + 128, stats + 192, g2, be2, scsh + 128, n);

    // layer 3
    k_gemm3<<<nb, 256, 0, stream>>>(B, W3, scsh + 128, dinv, hs3, n);
    k_agg4 <<<nb, 256, 0, stream>>>(hs3, rowptr, csr, dinv, b3, (float*)d_out, n);
}

// Round 7
// 345.817 us; speedup vs baseline: 1.4365x; 1.0077x over previous
//
#include <hip/hip_runtime.h>
#include <hip/hip_fp16.h>

#define IN_F 128
#define HID 64
#define NCLS 4
#define BN_EPS 1e-5f

#define MAXB 512        // max buckets (n <= 131072)
#define BSH 8           // bucket = dst >> 8  (256 nodes per bucket)
#define CHUNK 4096      // edges per block in chunked passes
#define BPP 1024        // blocks per channel-pass in k_agg64s

typedef float f32x4 __attribute__((ext_vector_type(4)));

// ---------------- CSR build ----------------

__global__ void k_init(float* __restrict__ stats, int* __restrict__ bhist) {
    int i = blockIdx.x * blockDim.x + threadIdx.x;
    if (i < 256) stats[i] = 0.f;
    if (i < MAXB) bhist[i] = 0;
}

// per-bucket histogram only (chunked, LDS-staged flush)
__global__ __launch_bounds__(256) void k_hist(const int* __restrict__ dst,
                                              int* __restrict__ bhist, int e) {
    __shared__ int lh[MAXB];
    int t = threadIdx.x;
    for (int i = t; i < MAXB; i += 256) lh[i] = 0;
    __syncthreads();
    int base = blockIdx.x * CHUNK;
    int m = min(CHUNK, e - base);
    for (int i = t; i < m; i += 256) atomicAdd(&lh[dst[base + i] >> BSH], 1);
    __syncthreads();
    for (int b = t; b < MAXB; b += 256) { int c = lh[b]; if (c) atomicAdd(&bhist[b], c); }
}

// exclusive scan of bucket histogram -> boff, bcur; also rowptr[n] = e
__global__ __launch_bounds__(512) void k_bscan(const int* __restrict__ bhist,
                                               int* __restrict__ boff,
                                               int* __restrict__ bcur,
                                               int* __restrict__ rowptr,
                                               int nbkt, int n, int e) {
    __shared__ int sh[512];
    int t = threadIdx.x;
    int v = (t < nbkt) ? bhist[t] : 0;
    sh[t] = v; __syncthreads();
    for (int off = 1; off < 512; off <<= 1) {
        int add = (t >= off) ? sh[t - off] : 0;
        __syncthreads();
        sh[t] += add;
        __syncthreads();
    }
    if (t < nbkt) { int ex = sh[t] - v; boff[t] = ex; bcur[t] = ex; }
    if (t == 0) { boff[nbkt] = e; rowptr[n] = e; }
}

// phase A: bin packed (src<<8 | dst&255) by dst-bucket, LDS multisplit, coalesced writes
__global__ __launch_bounds__(256) void k_bin(const int* __restrict__ src,
                                             const int* __restrict__ dst,
                                             int* __restrict__ bcur,
                                             unsigned* __restrict__ pairs, int e) {
    __shared__ uint2 stage[CHUNK];
    __shared__ int cnt[MAXB], off[MAXB], gbase[MAXB];
    int t = threadIdx.x;
    for (int i = t; i < MAXB; i += 256) cnt[i] = 0;
    __syncthreads();
    int base = blockIdx.x * CHUNK;
    int m = min(CHUNK, e - base);
    int lr[CHUNK / 256];
#pragma unroll
    for (int j = 0; j < CHUNK / 256; ++j) {
        int i = t + j * 256;
        if (i < m) lr[j] = atomicAdd(&cnt[dst[base + i] >> BSH], 1);
    }
    __syncthreads();
    // inclusive scan of cnt (512 entries, 256 threads, Hillis-Steele, 2/thread)
    off[t] = cnt[t]; off[t + 256] = cnt[t + 256];
    __syncthreads();
    for (int o = 1; o < 512; o <<= 1) {
        int v0 = (t >= o) ? off[t - o] : 0;
        int v1 = (t + 256 >= o) ? off[t + 256 - o] : 0;
        __syncthreads();
        off[t] += v0; off[t + 256] += v1;
        __syncthreads();
    }
    // reserve global range; bias so global addr = gbase[b] + stage_index
    for (int b = t; b < MAXB; b += 256) {
        int c = cnt[b];
        int ex = off[b] - c;                       // exclusive local offset
        gbase[b] = c ? (atomicAdd(&bcur[b], c) - ex) : 0;
    }
    __syncthreads();
#pragma unroll
    for (int j = 0; j < CHUNK / 256; ++j) {
        int i = t + j * 256;
        if (i < m) {
            int s = src[base + i], d = dst[base + i];
            int b = d >> BSH;
            stage[(off[b] - cnt[b]) + lr[j]] = make_uint2((unsigned)s, (unsigned)d);
        }
    }
    __syncthreads();
    for (int i = t; i < m; i += 256) {
        uint2 p = stage[i];
        int b = (int)(p.y >> BSH);
        pairs[gbase[b] + i] = (p.x << 8) | (p.y & 255u);
    }
}

// phase B: per-bucket (256 nodes) LDS degree-count + scan -> rowptr/dinv, then
// LDS-cursor scatter into csr.
__global__ __launch_bounds__(256) void k_bucket(const unsigned* __restrict__ pairs,
                                                const int* __restrict__ boff,
                                                int* __restrict__ rowptr,
                                                float* __restrict__ dinv,
                                                int* __restrict__ csr, int n) {
    __shared__ int deg[256], loff[256], cur[256];
    int b = blockIdx.x, t = threadIdx.x;
    deg[t] = 0;
    __syncthreads();
    int beg = boff[b], end = boff[b + 1];
    for (int i = beg + t; i < end; i += 256)
        atomicAdd(&deg[pairs[i] & 255u], 1);
    __syncthreads();
    int v = deg[t];
    loff[t] = v;
    __syncthreads();
    for (int o = 1; o < 256; o <<= 1) {
        int add = (t >= o) ? loff[t - o] : 0;
        __syncthreads();
        loff[t] += add;
        __syncthreads();
    }
    int ex = loff[t] - v;                 // exclusive in-bucket offset
    int node = b * 256 + t;
    if (node < n) {
        rowptr[node] = beg + ex;
        dinv[node] = 1.0f / sqrtf((float)(v + 1));   // deg includes self-loop
    }
    cur[t] = beg + ex;
    __syncthreads();
    for (int i = beg + t; i < end; i += 256) {
        unsigned p = pairs[i];
        int pos = atomicAdd(&cur[p & 255u], 1);
        csr[pos] = (int)(p >> 8);
    }
}

// ---------------- GEMMs (thread-per-row, W in LDS; fp16 pass-major output) ----------------
// Staged layout: hsA[pass][n][16] fp16  (pass = channel group of 16)

// hsA = half((x @ W1) * dinv)
__global__ __launch_bounds__(256) void k_gemm1(const float* __restrict__ x,
                                               const float* __restrict__ W,
                                               const float* __restrict__ dinv,
                                               __half* __restrict__ hsA, int n) {
    __shared__ float4 Ws[IN_F * HID / 4];   // 32 KB
    int t = threadIdx.x;
    const float4* W4 = (const float4*)W;
#pragma unroll
    for (int i = 0; i < 8; ++i) Ws[t + i * 256] = W4[t + i * 256];
    __syncthreads();
    int r = blockIdx.x * 256 + t;
    if (r >= n) return;
    float4 acc[16];
#pragma unroll
    for (int j = 0; j < 16; ++j) acc[j] = make_float4(0.f, 0.f, 0.f, 0.f);
    const float4* xr = (const float4*)(x + (size_t)r * IN_F);
    for (int kk = 0; kk < 32; ++kk) {
        float4 xv = xr[kk];
#pragma unroll
        for (int l = 0; l < 4; ++l) {
            float xs = (l == 0) ? xv.x : (l == 1) ? xv.y : (l == 2) ? xv.z : xv.w;
            const float4* wr = &Ws[(kk * 4 + l) * 16];
#pragma unroll
            for (int j = 0; j < 16; ++j) {
                float4 w = wr[j];
                acc[j].x += xs * w.x; acc[j].y += xs * w.y;
                acc[j].z += xs * w.z; acc[j].w += xs * w.w;
            }
        }
    }
    float dv = dinv[r];
    __half hv[64];
#pragma unroll
    for (int j = 0; j < 16; ++j) {
        hv[4 * j + 0] = __float2half_rn(acc[j].x * dv);
        hv[4 * j + 1] = __float2half_rn(acc[j].y * dv);
        hv[4 * j + 2] = __float2half_rn(acc[j].z * dv);
        hv[4 * j + 3] = __float2half_rn(acc[j].w * dv);
    }
#pragma unroll
    for (int p = 0; p < 4; ++p) {
        uint4* out = (uint4*)(hsA + ((size_t)p * n + r) * 16);
        out[0] = ((uint4*)hv)[p * 2 + 0];
        out[1] = ((uint4*)hv)[p * 2 + 1];
    }
}

// hsA = half((relu(z*sc+sh) @ W2) * dinv)
__global__ __launch_bounds__(256) void k_gemm2(const float* __restrict__ z,
                                               const float* __restrict__ W,
                                               const float* __restrict__ scsh,
                                               const float* __restrict__ dinv,
                                               __half* __restrict__ hsA, int n) {
    __shared__ float4 Ws[HID * HID / 4];    // 16 KB
    __shared__ float sc[64], sh[64];
    int t = threadIdx.x;
    const float4* W4 = (const float4*)W;
#pragma unroll
    for (int i = 0; i < 4; ++i) Ws[t + i * 256] = W4[t + i * 256];
    if (t < 64) { sc[t] = scsh[t]; sh[t] = scsh[64 + t]; }
    __syncthreads();
    int r = blockIdx.x * 256 + t;
    if (r >= n) return;
    float4 acc[16];
#pragma unroll
    for (int j = 0; j < 16; ++j) acc[j] = make_float4(0.f, 0.f, 0.f, 0.f);
    const float4* zr = (const float4*)(z + (size_t)r * HID);
    for (int kk = 0; kk < 16; ++kk) {
        float4 zv = zr[kk];
#pragma unroll
        for (int l = 0; l < 4; ++l) {
            int k = kk * 4 + l;
            float zs = (l == 0) ? zv.x : (l == 1) ? zv.y : (l == 2) ? zv.z : zv.w;
            float a = fmaxf(0.f, zs * sc[k] + sh[k]);
            const float4* wr = &Ws[k * 16];
#pragma unroll
            for (int j = 0; j < 16; ++j) {
                float4 w = wr[j];
                acc[j].x += a * w.x; acc[j].y += a * w.y;
                acc[j].z += a * w.z; acc[j].w += a * w.w;
            }
        }
    }
    float dv = dinv[r];
    __half hv[64];
#pragma unroll
    for (int j = 0; j < 16; ++j) {
        hv[4 * j + 0] = __float2half_rn(acc[j].x * dv);
        hv[4 * j + 1] = __float2half_rn(acc[j].y * dv);
        hv[4 * j + 2] = __float2half_rn(acc[j].z * dv);
        hv[4 * j + 3] = __float2half_rn(acc[j].w * dv);
    }
#pragma unroll
    for (int p = 0; p < 4; ++p) {
        uint4* out = (uint4*)(hsA + ((size_t)p * n + r) * 16);
        out[0] = ((uint4*)hv)[p * 2 + 0];
        out[1] = ((uint4*)hv)[p * 2 + 1];
    }
}

__global__ __launch_bounds__(256) void k_gemm3(const float* __restrict__ z,
                                               const float* __restrict__ W,
                                               const float* __restrict__ scsh,
                                               const float* __restrict__ dinv,
                                               float* __restrict__ hs3, int n) {
    __shared__ float4 Ws[64];
    __shared__ float sc[64], sh[64];
    int t = threadIdx.x;
    if (t < 64) { Ws[t] = ((const float4*)W)[t]; sc[t] = scsh[t]; sh[t] = scsh[64 + t]; }
    __syncthreads();
    int r = blockIdx.x * 256 + t;
    if (r >= n) return;
    float4 acc = make_float4(0.f, 0.f, 0.f, 0.f);
    const float4* zr = (const float4*)(z + (size_t)r * HID);
    for (int kk = 0; kk < 16; ++kk) {
        float4 zv = zr[kk];
#pragma unroll
        for (int l = 0; l < 4; ++l) {
            int k = kk * 4 + l;
            float zs = (l == 0) ? zv.x : (l == 1) ? zv.y : (l == 2) ? zv.z : zv.w;
            float a = fmaxf(0.f, zs * sc[k] + sh[k]);
            float4 w = Ws[k];
            acc.x += a * w.x; acc.y += a * w.y; acc.z += a * w.z; acc.w += a * w.w;
        }
    }
    float dv = dinv[r];
    ((float4*)hs3)[r] = make_float4(acc.x * dv, acc.y * dv, acc.z * dv, acc.w * dv);
}

// ---------------- Aggregation (CSR gather, fp16 source, channel-split) ----------------

__device__ inline float4 h4tof(uint2 r) {
    __half2 a = *reinterpret_cast<__half2*>(&r.x);
    __half2 b = *reinterpret_cast<__half2*>(&r.y);
    float2 fa = __half22float2(a), fb = __half22float2(b);
    return make_float4(fa.x, fa.y, fb.x, fb.y);
}

// 4 channel-passes, sequential cohorts of BPP blocks. Per pass the gathered
// segment hsA[pass] is 3.2 MB -> resident in each XCD's 4 MB L2. csr is
// nontemporal-loaded and z nontemporal-stored to keep the segment resident.
// 4 lanes per node (c4 = channel quad within the 16-ch segment).
__global__ __launch_bounds__(256) void k_agg64s(const __half* __restrict__ hsA,
                                                const int* __restrict__ rowptr,
                                                const int* __restrict__ csr,
                                                const float* __restrict__ dinv,
                                                const float* __restrict__ bias,
                                                float* __restrict__ z,
                                                float* __restrict__ sums,
                                                float* __restrict__ sumsq, int n) {
    __shared__ float lsum[16], lsq[16];
    int t = threadIdx.x;
    if (t < 16) { lsum[t] = 0.f; lsq[t] = 0.f; }
    __syncthreads();
    int pass = blockIdx.x / BPP;
    int pb   = blockIdx.x % BPP;
    const uint2* h2 = (const uint2*)(hsA + (size_t)pass * n * 16);  // 4 uint2 / row
    long long total = (long long)n * 4;
    int stride = BPP * 256;                 // multiple of 4 -> c4 invariant
    long long gid = (long long)pb * 256 + t;
    int c4 = (int)(gid & 3);
    float4 bv = ((const float4*)bias)[pass * 4 + c4];
    float ps0 = 0.f, ps1 = 0.f, ps2 = 0.f, ps3 = 0.f;
    float pq0 = 0.f, pq1 = 0.f, pq2 = 0.f, pq3 = 0.f;
    for (long long w = gid; w < total; w += stride) {
        int i = (int)(w >> 2);
        float4 a0 = h4tof(h2[(size_t)i * 4 + c4]);   // self-loop term
        float4 a1 = make_float4(0.f, 0.f, 0.f, 0.f);
        float4 a2 = make_float4(0.f, 0.f, 0.f, 0.f);
        float4 a3 = make_float4(0.f, 0.f, 0.f, 0.f);
        int beg = rowptr[i], end = rowptr[i + 1];
        int j = beg;
        for (; j + 4 <= end; j += 4) {
            int s0 = __builtin_nontemporal_load(csr + j);
            int s1 = __builtin_nontemporal_load(csr + j + 1);
            int s2 = __builtin_nontemporal_load(csr + j + 2);
            int s3 = __builtin_nontemporal_load(csr + j + 3);
            float4 v0 = h4tof(h2[(size_t)s0 * 4 + c4]);
            float4 v1 = h4tof(h2[(size_t)s1 * 4 + c4]);
            float4 v2 = h4tof(h2[(size_t)s2 * 4 + c4]);
            float4 v3 = h4tof(h2[(size_t)s3 * 4 + c4]);
            a0.x += v0.x; a0.y += v0.y; a0.z += v0.z; a0.w += v0.w;
            a1.x += v1.x; a1.y += v1.y; a1.z += v1.z; a1.w += v1.w;
            a2.x += v2.x; a2.y += v2.y; a2.z += v2.z; a2.w += v2.w;
            a3.x += v3.x; a3.y += v3.y; a3.z += v3.z; a3.w += v3.w;
        }
        for (; j < end; ++j) {
            int s = __builtin_nontemporal_load(csr + j);
            float4 v = h4tof(h2[(size_t)s * 4 + c4]);
            a0.x += v.x; a0.y += v.y; a0.z += v.z; a0.w += v.w;
        }
        float4 acc = make_float4((a0.x + a1.x) + (a2.x + a3.x),
                                 (a0.y + a1.y) + (a2.y + a3.y),
                                 (a0.z + a1.z) + (a2.z + a3.z),
                                 (a0.w + a1.w) + (a2.w + a3.w));
        float dv = dinv[i];
        f32x4 zq;
        zq[0] = acc.x * dv + bv.x; zq[1] = acc.y * dv + bv.y;
        zq[2] = acc.z * dv + bv.z; zq[3] = acc.w * dv + bv.w;
        __builtin_nontemporal_store(zq, (f32x4*)(z + (size_t)i * 64 + pass * 16 + c4 * 4));
        ps0 += zq[0]; ps1 += zq[1]; ps2 += zq[2]; ps3 += zq[3];
        pq0 += zq[0] * zq[0]; pq1 += zq[1] * zq[1];
        pq2 += zq[2] * zq[2]; pq3 += zq[3] * zq[3];
    }
    int cb = c4 * 4;
    atomicAdd(&lsum[cb + 0], ps0); atomicAdd(&lsum[cb + 1], ps1);
    atomicAdd(&lsum[cb + 2], ps2); atomicAdd(&lsum[cb + 3], ps3);
    atomicAdd(&lsq[cb + 0], pq0);  atomicAdd(&lsq[cb + 1], pq1);
    atomicAdd(&lsq[cb + 2], pq2);  atomicAdd(&lsq[cb + 3], pq3);
    __syncthreads();
    if (t < 16) {
        atomicAdd(&sums[pass * 16 + t], lsum[t]);
        atomicAdd(&sumsq[pass * 16 + t], lsq[t]);
    }
}

__global__ void k_agg4(const float* __restrict__ hs3, const int* __restrict__ rowptr,
                       const int* __restrict__ csr, const float* __restrict__ dinv,
                       const float* __restrict__ b3, float* __restrict__ out, int n) {
    int i = blockIdx.x * blockDim.x + threadIdx.x;
    if (i >= n) return;
    const float4* h4 = (const float4*)hs3;
    float4 a0 = h4[i];
    float4 a1 = make_float4(0.f, 0.f, 0.f, 0.f);
    float4 a2 = make_float4(0.f, 0.f, 0.f, 0.f);
    float4 a3 = make_float4(0.f, 0.f, 0.f, 0.f);
    int beg = rowptr[i], end = rowptr[i + 1];
    int j = beg;
    for (; j + 4 <= end; j += 4) {
        int s0 = csr[j], s1 = csr[j + 1], s2 = csr[j + 2], s3 = csr[j + 3];
        float4 v0 = h4[s0], v1 = h4[s1], v2 = h4[s2], v3 = h4[s3];
        a0.x += v0.x; a0.y += v0.y; a0.z += v0.z; a0.w += v0.w;
        a1.x += v1.x; a1.y += v1.y; a1.z += v1.z; a1.w += v1.w;
        a2.x += v2.x; a2.y += v2.y; a2.z += v2.z; a2.w += v2.w;
        a3.x += v3.x; a3.y += v3.y; a3.z += v3.z; a3.w += v3.w;
    }
    for (; j < end; ++j) {
        float4 v = h4[csr[j]];
        a0.x += v.x; a0.y += v.y; a0.z += v.z; a0.w += v.w;
    }
    float4 acc = make_float4((a0.x + a1.x) + (a2.x + a3.x),
                             (a0.y + a1.y) + (a2.y + a3.y),
                             (a0.z + a1.z) + (a2.z + a3.z),
                             (a0.w + a1.w) + (a2.w + a3.w));
    float dv = dinv[i];
    float4 bv = *(const float4*)b3;
    ((float4*)out)[i] = make_float4(acc.x * dv + bv.x, acc.y * dv + bv.y,
                                    acc.z * dv + bv.z, acc.w * dv + bv.w);
}

__global__ void k_bnstats(const float* __restrict__ sums, const float* __restrict__ sumsq,
                          const float* __restrict__ g, const float* __restrict__ be,
                          float* __restrict__ scsh, int n) {
    int t = threadIdx.x;
    if (t < 64) {
        float inv_n = 1.f / (float)n;
        float m = sums[t] * inv_n;
        float v = sumsq[t] * inv_n - m * m;
        float sc = g[t] / sqrtf(v + BN_EPS);
        scsh[t] = sc;
        scsh[64 + t] = be[t] - m * sc;
    }
}

// ---------------- launch ----------------

extern "C" void kernel_launch(void* const* d_in, const int* in_sizes, int n_in,
                              void* d_out, int out_size, void* d_ws, size_t ws_size,
                              hipStream_t stream) {
    const float* x   = (const float*)d_in[0];
    const int*   ei  = (const int*)d_in[1];
    const float* W1  = (const float*)d_in[2];
    const float* b1  = (const float*)d_in[3];
    const float* g1  = (const float*)d_in[4];
    const float* be1 = (const float*)d_in[5];
    const float* W2  = (const float*)d_in[6];
    const float* b2  = (const float*)d_in[7];
    const float* g2  = (const float*)d_in[8];
    const float* be2 = (const float*)d_in[9];
    const float* W3  = (const float*)d_in[10];
    const float* b3  = (const float*)d_in[11];

    int n = in_sizes[0] / IN_F;
    int e = in_sizes[1] / 2;
    const int* src = ei;
    const int* dst = ei + e;

    float* wsf = (float*)d_ws;
    size_t NP = ((size_t)(n + 256) + 255) & ~(size_t)255;   // >= n+1
    size_t EP = ((size_t)e + 255) & ~(size_t)255;
    size_t NB = (((size_t)n * HID) + 255) & ~(size_t)255;

    float* stats  = wsf;                   // 256
    float* scsh   = wsf + 256;             // 256
    int*   bhist  = (int*)(wsf + 512);     // 512
    int*   boff   = bhist + 512;           // 520
    int*   bcur   = boff + 520;            // 512
    int*   rowptr = bcur + 512;            // NP ints
    float* dinv   = (float*)(rowptr + NP); // NP floats
    int*   csr    = (int*)(dinv + NP);     // EP ints
    float* A      = (float*)(csr + EP);    // staged features: __half [4][n][16]
    float* B      = A + NB;                // z buffer fp32 [n,64]
    float* hs3    = B + NB;                // [n,4]
    unsigned* pairs = (unsigned*)B;        // alias: B first written after k_bucket
    __half* Ah    = (__half*)A;

    int nb = (n + 255) / 256;
    int eb = (e + CHUNK - 1) / CHUNK;      // chunked edge blocks
    int nbkt = (n + 255) >> BSH;           // buckets (<= MAXB)

    k_init  <<<2, 256, 0, stream>>>(stats, bhist);
    k_hist  <<<eb, 256, 0, stream>>>(dst, bhist, e);
    k_bscan <<<1, 512, 0, stream>>>(bhist, boff, bcur, rowptr, nbkt, n, e);
    k_bin   <<<eb, 256, 0, stream>>>(src, dst, bcur, pairs, e);
    k_bucket<<<nbkt, 256, 0, stream>>>(pairs, boff, rowptr, dinv, csr, n);

    // layer 1
    k_gemm1<<<nb, 256, 0, stream>>>(x, W1, dinv, Ah, n);
    k_agg64s<<<4 * BPP, 256, 0, stream>>>(Ah, rowptr, csr, dinv, b1, B, stats, stats + 64, n);
    k_bnstats<<<1, 64, 0, stream>>>(stats, stats + 64, g1, be1, scsh, n);

    // layer 2
    k_gemm2<<<nb, 256, 0, stream>>>(B, W2, scsh, dinv, Ah, n);
    k_agg64s<<<4 * BPP, 256, 0, stream>>>(Ah, rowptr, csr, dinv, b2, B, stats + 128, stats + 192, n);
    k_bnstats<<<1, 64, 0, stream>>>(stats + 128, stats + 192, g2, be2, scsh + 128, n);

    // layer 3
    k_gemm3<<<nb, 256, 0, stream>>>(B, W3, scsh + 128, dinv, hs3, n);
    k_agg4 <<<nb, 256, 0, stream>>>(hs3, rowptr, csr, dinv, b3, (float*)d_out, n);
}